// Round 14
// baseline (126.790 us; speedup 1.0000x reference)
//
#include <hip/hip_runtime.h>

// out[b] = sum_g exp(-(||x_b||^2+||c_g||^2-2 x_b.c_g)/2) * w[g]
// B=16384, G=8192, D=64 fp32.
// v14: producer/consumer waves, CONVERGENT barriers. R13's race = barriers
// inside divergent if(w<4) branches (UB -> compiler may move LDS ops across).
// Now ONE uniform loop, all __syncthreads at top level; role work in
// barrier-free guarded regions. B staged to LDS via global_load_lds (0 VGPR,
// 2 frags/wave, double-buffered); acc handoff = single 32KB buffer,
// 2 barriers/tile: ph1 {stage B(t+1) || P: MFMA t || C: EPI t-1},
// ph2 {P: write acc t}. 4P+4C waves, 128 rows x 64 cols/tile, GSPLIT=4,
// grid 512 = 2 blocks/CU (66KB LDS). No SGB, no setprio, no raw barriers.

typedef __attribute__((ext_vector_type(8))) short short8v;
typedef __attribute__((ext_vector_type(16))) float f32x16;
typedef unsigned short u16;
typedef unsigned int u32;

#define L2E   1.4426950408889634f
#define NHL2E 0.72134752044448170f   // log2(e)/2
#define GSPLIT 4                     // 2048 cols per block, 32 tiles of 64

__device__ __forceinline__ u16 f2bf(float x){
  u32 u = __float_as_uint(x);
  return (u16)((u + 0x7FFFu + ((u >> 16) & 1u)) >> 16);   // RNE
}
__device__ __forceinline__ float bf2f(u16 h){ return __uint_as_float(((u32)h) << 16); }

__device__ __forceinline__ void gl_lds16(const void* g, void* l){
  __builtin_amdgcn_global_load_lds((const __attribute__((address_space(1))) u32*)g,
                                   (__attribute__((address_space(3))) u32*)l, 16, 0, 0);
}

#define MFMA(a,b,c) __builtin_amdgcn_mfma_f32_32x32x16_bf16(a,b,c,0,0,0)

// ---- one-time: C [G][64] fp32 -> hi/lo bf16 in fragment order + (cn,w) ----
// frag unit (cg=g/32, f): byte base = cg*4096 + f*1024 + l*16
__global__ __launch_bounds__(256)
void convert_C(const float* __restrict__ C, const float* __restrict__ W,
               u16* __restrict__ Chi, u16* __restrict__ Clo,
               float2* __restrict__ cw, int G){
  int idx = blockIdx.x*256 + threadIdx.x;
  int g = idx >> 2, f = idx & 3;
  if (g >= G) return;
  const float* row = C + (size_t)g*64 + f*16;
  int cg = g >> 5, cl = g & 31;
  float norm = 0.f;
  u16 hb[16], lb[16];
  #pragma unroll
  for (int q=0; q<4; q++){
    float4 v = *(const float4*)(row + q*4);
    float xv[4] = {v.x, v.y, v.z, v.w};
    #pragma unroll
    for (int e=0; e<4; e++){
      float x = xv[e];
      norm = fmaf(x, x, norm);
      u16 hh = f2bf(x); hb[q*4+e] = hh;
      lb[q*4+e] = f2bf(x - bf2f(hh));
    }
  }
  norm += __shfl_xor(norm, 1);
  norm += __shfl_xor(norm, 2);
  size_t u = ((size_t)(cg*4 + f)*64 + cl)*8;
  *(short8v*)(Chi + u)        = *(short8v*)hb;        // h=0 (k 0..7)
  *(short8v*)(Chi + u + 256)  = *(short8v*)(hb + 8);  // h=1 (k 8..15)
  *(short8v*)(Clo + u)        = *(short8v*)lb;
  *(short8v*)(Clo + u + 256)  = *(short8v*)(lb + 8);
  if (f == 0) cw[g] = make_float2(-NHL2E*norm, W[g]);
}

__global__ __launch_bounds__(512, 4)
void rbf_pc(const float* __restrict__ X, const u16* __restrict__ Chi,
            const u16* __restrict__ Clo, const float2* __restrict__ cw,
            float* __restrict__ out){
  __shared__ __align__(16) float accb[64][128];   // acc handoff, 32KB, swizzled rows
  __shared__ short8v Bs[2][16][64];               // B dbuf: 16 frags x 1KB, 32KB
  __shared__ float xnl[128];

  const int tid = threadIdx.x;
  const int l  = tid & 63;
  const int cl = l & 31;
  const int h  = l >> 5;
  const int w  = tid >> 6;           // 0-3 producers, 4-7 consumers
  const bool isP = (w < 4);
  const int cs = w - 4;              // consumer row-group (when !isP)
  const int b = blockIdx.x;
  const int gp = b & 3;
  const int rows0 = (b >> 2) * 128;
  const int g0 = gp * 2048;

  const char* gH = (const char*)Chi;
  const char* gL = (const char*)Clo;

  short8v ah[4], al[4];
  float racc[32];
  f32x16 a0, a1;

  // ---- prologue (barrier-free role work) ----
  if (isP){
    const float* xr = X + (size_t)(rows0 + w*32 + cl)*64;
    float s = 0.f;
    #pragma unroll
    for (int f=0; f<4; f++){
      float4 v0 = *(const float4*)(xr + f*16 + h*8);
      float4 v1 = *(const float4*)(xr + f*16 + h*8 + 4);
      float xv[8] = {v0.x,v0.y,v0.z,v0.w,v1.x,v1.y,v1.z,v1.w};
      u16 hb[8], lb[8];
      #pragma unroll
      for (int e=0;e<8;e++){
        float x = xv[e];
        s = fmaf(x, x, s);
        u16 hh = f2bf(x); hb[e]=hh;
        lb[e] = f2bf(x - bf2f(hh));
      }
      ah[f] = *(short8v*)hb;
      al[f] = *(short8v*)lb;
    }
    s += __shfl_xor(s, 32);
    if (l < 32) xnl[w*32 + l] = -NHL2E * s;
  } else {
    #pragma unroll
    for (int r=0;r<32;++r) racc[r] = 0.f;
  }
  // stage B tile 0: each wave stages frag w (hi) + frag w+8 (lo)
  {
    const size_t tb = (size_t)(gp*64)*4096 + (size_t)w*1024 + (size_t)l*16;
    gl_lds16(gH + tb, &Bs[0][w][0]);
    gl_lds16(gL + tb, &Bs[0][w+8][0]);
  }
  __syncthreads();   // uniform; drains staging

  #pragma unroll 1
  for (int t = 0; t <= 32; ++t){
    // ======== phase 1: stage B(t+1) || P: MFMA tile t || C: EPI t-1 ========
    if (t < 31){
      const size_t tb = (size_t)(gp*64 + (t+1)*2)*4096 + (size_t)w*1024 + (size_t)l*16;
      const int nb = (t+1) & 1;
      gl_lds16(gH + tb, &Bs[nb][w][0]);
      gl_lds16(gL + tb, &Bs[nb][w+8][0]);
    }
    if (isP){
      if (t < 32){
        const short8v* bb = &Bs[t & 1][0][0];
        a0 = (f32x16){}; a1 = (f32x16){};
        #pragma unroll
        for (int f=0; f<4; ++f){
          short8v bh0 = bb[f*64      + l];
          short8v bh1 = bb[(4+f)*64  + l];
          short8v bl0 = bb[(8+f)*64  + l];
          short8v bl1 = bb[(12+f)*64 + l];
          a0 = MFMA(ah[f], bh0, a0);
          a1 = MFMA(ah[f], bh1, a1);
          a0 = MFMA(ah[f], bl0, a0);
          a1 = MFMA(ah[f], bl1, a1);
          a0 = MFMA(al[f], bh0, a0);
          a1 = MFMA(al[f], bh1, a1);
        }
      }
    } else {
      if (t > 0){
        const int tt = t - 1;
        const float2 cwv = cw[g0 + tt*64 + l];
        const float* cb = &accb[l][0];
        #pragma unroll
        for (int j=0; j<8; ++j){
          const int rp = (cs*32 + 4*j) ^ ((l & 7) << 2);
          const float4 p = *(const float4*)(cb + rp);
          racc[4*j+0] = fmaf(__builtin_amdgcn_exp2f(fmaf(p.x, L2E, cwv.x)), cwv.y, racc[4*j+0]);
          racc[4*j+1] = fmaf(__builtin_amdgcn_exp2f(fmaf(p.y, L2E, cwv.x)), cwv.y, racc[4*j+1]);
          racc[4*j+2] = fmaf(__builtin_amdgcn_exp2f(fmaf(p.z, L2E, cwv.x)), cwv.y, racc[4*j+2]);
          racc[4*j+3] = fmaf(__builtin_amdgcn_exp2f(fmaf(p.w, L2E, cwv.x)), cwv.y, racc[4*j+3]);
        }
      }
    }
    __syncthreads();   // uniform: consumers done with tile t-1; acc buffer free

    // ======== phase 2: P writes acc tile t (swizzled) ========
    if (isP && t < 32){
      #pragma unroll
      for (int cf=0; cf<2; ++cf){
        const int col = cf*32 + cl;
        float* cb = &accb[col][0];
        #pragma unroll
        for (int k=0; k<4; ++k){
          const int rb = w*32 + 8*k + 4*h;
          const int rp = rb ^ ((col & 7) << 2);
          float4 v;
          if (cf == 0) v = make_float4(a0[4*k], a0[4*k+1], a0[4*k+2], a0[4*k+3]);
          else         v = make_float4(a1[4*k], a1[4*k+1], a1[4*k+2], a1[4*k+3]);
          *(float4*)(cb + rp) = v;
        }
      }
    }
    __syncthreads();   // uniform: tile t sealed for consumers
  }

  // ---- consumers: reduce rows over 64 col-lanes, fold 2^xn, atomic ----
  if (!isP){
    #pragma unroll
    for (int rr=0; rr<32; ++rr){
      float v = racc[rr];
      v += __shfl_xor(v, 1);
      v += __shfl_xor(v, 2);
      v += __shfl_xor(v, 4);
      v += __shfl_xor(v, 8);
      v += __shfl_xor(v, 16);
      v += __shfl_xor(v, 32);
      if (l == 0)
        atomicAdd(&out[rows0 + cs*32 + rr],
                  v * __builtin_amdgcn_exp2f(xnl[cs*32 + rr]));
    }
  }
}

extern "C" void kernel_launch(void* const* d_in, const int* in_sizes, int n_in,
                              void* d_out, int out_size, void* d_ws, size_t ws_size,
                              hipStream_t stream) {
  const float* X = (const float*)d_in[0];   // [B,64]
  const float* C = (const float*)d_in[1];   // [G,64]
  const float* W = (const float*)d_in[2];   // [G]
  float* out = (float*)d_out;               // [B]
  const int B = in_sizes[0] / 64;
  const int G = in_sizes[2];

  u16* Chi = (u16*)d_ws;                         // 1 MB
  u16* Clo = Chi + (size_t)G*64;                 // 1 MB
  float2* cw = (float2*)(Clo + (size_t)G*64);    // 64 KB

  hipMemsetAsync(out, 0, (size_t)B*sizeof(float), stream);
  convert_C<<<(G*4)/256, 256, 0, stream>>>(C, W, Chi, Clo, cw, G);
  rbf_pc<<<(B/128)*GSPLIT, 512, 0, stream>>>(X, Chi, Clo, cw, out);
}

// Round 15
// 48.548 us; speedup vs baseline: 2.6116x; 2.6116x over previous
//
#include <hip/hip_runtime.h>

// out[b] = sum_g exp(-(||x_b||^2+||c_g||^2-2 x_b.c_g)/2) * w[g]
// B=16384, G=8192, D=64 fp32.
// v15: SINGLE-PASS F16 MFMA. f16 mantissa = 11 bits: dot error std ~3e-3 in
// the exponent -> absmax ~1e-11 vs 5.8e-11 threshold (norms stay exact fp32).
// Cuts MFMA work 3x (floor 21->7us) and B traffic 2x vs split-bf16.
// Skeleton = R12's passing structure verbatim: zero LDS, zero barriers,
// B depth-1 register ping-pong, E/O acc sets with EPI hand-interleaved
// (4 EPIX per MFMA), no setprio / no sched_group_barrier (R11 poison).
// Trans pipe (134M v_exp_f32 ~= 13.7us) is now the theoretical floor.

typedef __attribute__((ext_vector_type(8))) _Float16 half8v;
typedef __attribute__((ext_vector_type(16))) float f32x16;
typedef unsigned short u16;
typedef unsigned int u32;

#define L2E   1.4426950408889634f
#define NHL2E 0.72134752044448170f   // log2(e)/2
#define GSPLIT 8                     // 1024 cols per wave sweep, 32 tiles

#define MFMA(a,b,c) __builtin_amdgcn_mfma_f32_32x32x16_f16(a,b,c,0,0,0)

// ---- one-time: C [G][64] fp32 -> f16 in MFMA fragment order + (cn,w) ----
// frag unit (cg=g/32, f): byte base = cg*4096 + f*1024 + l*16 (8 f16/lane)
__global__ __launch_bounds__(256)
void convert_C(const float* __restrict__ C, const float* __restrict__ W,
               _Float16* __restrict__ Cf, float2* __restrict__ cw, int G){
  int idx = blockIdx.x*256 + threadIdx.x;
  int g = idx >> 2, f = idx & 3;
  if (g >= G) return;
  const float* row = C + (size_t)g*64 + f*16;
  int cg = g >> 5, cl = g & 31;
  float norm = 0.f;
  _Float16 hv[16];
  #pragma unroll
  for (int q=0; q<4; q++){
    float4 v = *(const float4*)(row + q*4);
    float xv[4] = {v.x, v.y, v.z, v.w};
    #pragma unroll
    for (int e=0; e<4; e++){
      float x = xv[e];
      norm = fmaf(x, x, norm);
      hv[q*4+e] = (_Float16)x;       // RNE f32->f16
    }
  }
  norm += __shfl_xor(norm, 1);       // reduce over the 4 f-lanes of this g
  norm += __shfl_xor(norm, 2);
  size_t u = ((size_t)(cg*4 + f)*64 + cl)*8;
  *(half8v*)(Cf + u)       = *(half8v*)hv;        // h=0 (k 0..7)
  *(half8v*)(Cf + u + 256) = *(half8v*)(hv + 8);  // h=1 (k 8..15)
  if (f == 0) cw[g] = make_float2(-NHL2E*norm, W[g]);
}

__global__ __launch_bounds__(256, 2)
void rbf_mfma(const float* __restrict__ X, const _Float16* __restrict__ Cf,
              const float2* __restrict__ cw, float* __restrict__ out){
  const int tid = threadIdx.x;
  const int l  = tid & 63;
  const int cl = l & 31;
  const int h  = l >> 5;
  const int w  = tid >> 6;
  const int b  = blockIdx.x;
  const int gp = b & 7;                  // 4 waves share gp -> L1/L2 B-sharing
  const int rows0 = ((b >> 3)*4 + w) * 64;

  // ---- A: 64 rows (2 rowfrags) f16 in registers + fp32 row norms ----
  half8v af[2][4];
  float xn[2];
  #pragma unroll
  for (int rf=0; rf<2; rf++){
    const float* xr = X + (size_t)(rows0 + rf*32 + cl)*64;
    float s = 0.f;
    #pragma unroll
    for (int f=0; f<4; f++){
      float4 v0 = *(const float4*)(xr + f*16 + h*8);
      float4 v1 = *(const float4*)(xr + f*16 + h*8 + 4);
      float xv[8] = {v0.x,v0.y,v0.z,v0.w,v1.x,v1.y,v1.z,v1.w};
      _Float16 hv[8];
      #pragma unroll
      for (int e=0;e<8;e++){
        float x = xv[e];
        s = fmaf(x, x, s);
        hv[e] = (_Float16)x;
      }
      af[rf][f] = *(half8v*)hv;
    }
    // this lane's 8 k-values + the other half's 8 (h^1) live at lane^32
    s += __shfl_xor(s, 32);
    xn[rf] = -NHL2E * s;
  }

  // B stream: byte addr = t*4096 + f*1024 + l*16 within this gp part
  const char* baseF = (const char*)Cf + (size_t)gp*131072 + (size_t)l*16;
  const float2* cwp = cw + gp*1024 + cl;

  half8v bf[2];
  bf[0] = *(const half8v*)baseF;         // (t=0, f=0)

  float racc0[16], racc1[16];
  #pragma unroll
  for (int r=0;r<16;r++){ racc0[r]=0.f; racc1[r]=0.f; }

  f32x16 aE0, aE1, aO0, aO1;
  float2 cwE, cwO;

  // one epilogue element: RACC[R] += 2^(L2E*P[R] + CWV.x) * CWV.y
  #define EPIX(P, R, CWV, RACC)                                             \
    RACC[R] = fmaf(__builtin_amdgcn_exp2f(fmaf(P[R], L2E, CWV.x)),          \
                   CWV.y, RACC[R])

  // tile T: 8 MFMA into (C0,C1); EPI of prev tile interleaved 4 per MFMA.
  #define TILE(T, C0, C1, P0, P1, CWC, CWP, DO_EPI) do {                    \
    const int t_ = (T);                                                     \
    CWC = cwp[t_*32];                                                       \
    C0 = (f32x16){}; C1 = (f32x16){};                                       \
    _Pragma("unroll")                                                       \
    for (int f=0; f<4; ++f){                                                \
      const int p = f & 1, q = p ^ 1;                                       \
      const int nf = (f + 1) & 3;                                           \
      const int nt = (f == 3) ? ((t_ + 1) & 31) : t_;                       \
      bf[q] = *(const half8v*)(baseF + (size_t)nt*4096 + (size_t)nf*1024);  \
      C0 = MFMA(af[0][f], bf[p], C0);                                       \
      if (DO_EPI){                                                          \
        EPIX(P0, f*4+0, CWP, racc0); EPIX(P1, f*4+0, CWP, racc1);           \
        EPIX(P0, f*4+1, CWP, racc0); EPIX(P1, f*4+1, CWP, racc1);           \
      }                                                                     \
      C1 = MFMA(af[1][f], bf[p], C1);                                       \
      if (DO_EPI){                                                          \
        EPIX(P0, f*4+2, CWP, racc0); EPIX(P1, f*4+2, CWP, racc1);           \
        EPIX(P0, f*4+3, CWP, racc0); EPIX(P1, f*4+3, CWP, racc1);           \
      }                                                                     \
    }                                                                       \
  } while(0)

  TILE(0, aE0, aE1, aO0, aO1, cwE, cwO, 0);     // prologue: no EPI yet
  #pragma unroll 1
  for (int tp = 0; tp < 15; ++tp){
    TILE(2*tp + 1, aO0, aO1, aE0, aE1, cwO, cwE, 1);
    TILE(2*tp + 2, aE0, aE1, aO0, aO1, cwE, cwO, 1);
  }
  TILE(31, aO0, aO1, aE0, aE1, cwO, cwE, 1);    // EPIs tile 30
  #pragma unroll
  for (int r=0;r<16;++r){                       // final EPI: tile 31
    EPIX(aO0, r, cwO, racc0);
    EPIX(aO1, r, cwO, racc1);
  }
  #undef TILE
  #undef EPIX

  // ---- reduce over 32 col-lanes, fold 2^xn, one atomic per row ----
  #pragma unroll
  for (int rf=0; rf<2; rf++){
    #pragma unroll
    for (int r=0;r<16;r++){
      float v = rf ? racc1[r] : racc0[r];
      v += __shfl_xor(v, 1);
      v += __shfl_xor(v, 2);
      v += __shfl_xor(v, 4);
      v += __shfl_xor(v, 8);
      v += __shfl_xor(v, 16);
      const int rit = (r&3) + 8*(r>>2) + 4*h;
      const float xnv = __shfl(xn[rf], rit);
      if (cl == 0)
        atomicAdd(&out[rows0 + rf*32 + rit], v * __builtin_amdgcn_exp2f(xnv));
    }
  }
}

extern "C" void kernel_launch(void* const* d_in, const int* in_sizes, int n_in,
                              void* d_out, int out_size, void* d_ws, size_t ws_size,
                              hipStream_t stream) {
  const float* X = (const float*)d_in[0];   // [B,64]
  const float* C = (const float*)d_in[1];   // [G,64]
  const float* W = (const float*)d_in[2];   // [G]
  float* out = (float*)d_out;               // [B]
  const int B = in_sizes[0] / 64;
  const int G = in_sizes[2];

  _Float16* Cf = (_Float16*)d_ws;                // 1 MB, fragment-ordered
  float2* cw = (float2*)(Cf + (size_t)G*64);     // 64 KB

  hipMemsetAsync(out, 0, (size_t)B*sizeof(float), stream);
  convert_C<<<(G*4)/256, 256, 0, stream>>>(C, W, Cf, cw, G);
  rbf_mfma<<<(B/256)*GSPLIT, 256, 0, stream>>>(X, Cf, cw, out);
}

// Round 16
// 48.262 us; speedup vs baseline: 2.6271x; 1.0059x over previous
//
#include <hip/hip_runtime.h>

// out[b] = sum_g exp(-(||x_b||^2+||c_g||^2-2 x_b.c_g)/2) * w[g]
// B=16384, G=8192, D=64 fp32.
// v16 = v15 (single-pass f16 MFMA, absmax 1.5e-11 vs 5.8e-11 thr) + TLP:
// GSPLIT=12 (22/21-tile uneven split), grid 768 = 3 blocks/CU at
// __launch_bounds__(256,3). v15's VGPR=80 (accs in AGPR, ~144 total) fits
// the 170-reg budget -> no R6-style prefetch demotion expected.
// Trans pipe (134M v_exp_f32 ~= 13.7us/SIMD) is the floor; 3 waves/SIMD
// from different phases saturate it. No SGB / no setprio / no barriers.

typedef __attribute__((ext_vector_type(8))) _Float16 half8v;
typedef __attribute__((ext_vector_type(16))) float f32x16;
typedef unsigned short u16;
typedef unsigned int u32;

#define L2E   1.4426950408889634f
#define NHL2E 0.72134752044448170f   // log2(e)/2
#define GP 12                        // col parts: gp<4 -> 22 tiles, else 21

#define MFMA(a,b,c) __builtin_amdgcn_mfma_f32_32x32x16_f16(a,b,c,0,0,0)

// ---- one-time: C [G][64] fp32 -> f16 in MFMA fragment order + (cn,w) ----
// frag unit (cg=g/32, f): byte base = cg*4096 + f*1024 + l*16 (8 f16/lane)
__global__ __launch_bounds__(256)
void convert_C(const float* __restrict__ C, const float* __restrict__ W,
               _Float16* __restrict__ Cf, float2* __restrict__ cw, int G){
  int idx = blockIdx.x*256 + threadIdx.x;
  int g = idx >> 2, f = idx & 3;
  if (g >= G) return;
  const float* row = C + (size_t)g*64 + f*16;
  int cg = g >> 5, cl = g & 31;
  float norm = 0.f;
  _Float16 hv[16];
  #pragma unroll
  for (int q=0; q<4; q++){
    float4 v = *(const float4*)(row + q*4);
    float xv[4] = {v.x, v.y, v.z, v.w};
    #pragma unroll
    for (int e=0; e<4; e++){
      float x = xv[e];
      norm = fmaf(x, x, norm);
      hv[q*4+e] = (_Float16)x;       // RNE f32->f16
    }
  }
  norm += __shfl_xor(norm, 1);       // reduce over the 4 f-lanes of this g
  norm += __shfl_xor(norm, 2);
  size_t u = ((size_t)(cg*4 + f)*64 + cl)*8;
  *(half8v*)(Cf + u)       = *(half8v*)hv;        // h=0 (k 0..7)
  *(half8v*)(Cf + u + 256) = *(half8v*)(hv + 8);  // h=1 (k 8..15)
  if (f == 0) cw[g] = make_float2(-NHL2E*norm, W[g]);
}

__global__ __launch_bounds__(256, 3)
void rbf_mfma(const float* __restrict__ X, const _Float16* __restrict__ Cf,
              const float2* __restrict__ cw, float* __restrict__ out){
  const int tid = threadIdx.x;
  const int l  = tid & 63;
  const int cl = l & 31;
  const int h  = l >> 5;
  const int w  = tid >> 6;
  const int b  = blockIdx.x;
  const int gp = b % GP;               // 4 waves share gp -> L1/L2 B-sharing
  const int rows0 = (b / GP) * 256 + w * 64;

  // global col-tile range for this part (256 tiles of 32 cols over G)
  const int t0  = gp * 21 + (gp < 4 ? gp : 4);
  const int ntl = (gp < 4) ? 22 : 21;

  // ---- A: 64 rows (2 rowfrags) f16 in registers + fp32 row norms ----
  half8v af[2][4];
  float xn[2];
  #pragma unroll
  for (int rf=0; rf<2; rf++){
    const float* xr = X + (size_t)(rows0 + rf*32 + cl)*64;
    float s = 0.f;
    #pragma unroll
    for (int f=0; f<4; f++){
      float4 v0 = *(const float4*)(xr + f*16 + h*8);
      float4 v1 = *(const float4*)(xr + f*16 + h*8 + 4);
      float xv[8] = {v0.x,v0.y,v0.z,v0.w,v1.x,v1.y,v1.z,v1.w};
      _Float16 hv[8];
      #pragma unroll
      for (int e=0;e<8;e++){
        float x = xv[e];
        s = fmaf(x, x, s);
        hv[e] = (_Float16)x;
      }
      af[rf][f] = *(half8v*)hv;
    }
    s += __shfl_xor(s, 32);
    xn[rf] = -NHL2E * s;
  }

  // B stream: byte addr = T*4096 + f*1024 + l*16 (T = global col-tile)
  const char* baseF = (const char*)Cf + (size_t)l*16;
  const float2* cwp = cw + cl;

  half8v bf[2];
  bf[0] = *(const half8v*)(baseF + (size_t)t0*4096);   // (t0, f=0)

  float racc0[16], racc1[16];
  #pragma unroll
  for (int r=0;r<16;r++){ racc0[r]=0.f; racc1[r]=0.f; }

  f32x16 aE0, aE1, aO0, aO1;
  float2 cwE, cwO;

  // one epilogue element: RACC[R] += 2^(L2E*P[R] + CWV.x) * CWV.y
  #define EPIX(P, R, CWV, RACC)                                             \
    RACC[R] = fmaf(__builtin_amdgcn_exp2f(fmaf(P[R], L2E, CWV.x)),          \
                   CWV.y, RACC[R])

  // tile T (runtime), TN = next tile to prefetch toward; 8 MFMA into
  // (C0,C1); EPI of prev tile interleaved 4 per MFMA. Ping-pong parity
  // is static (f&1).
  #define TILE(T, TN, C0, C1, P0, P1, CWC, CWP, DO_EPI) do {                \
    const int t_ = (T), tn_ = (TN);                                         \
    CWC = cwp[t_*32];                                                       \
    C0 = (f32x16){}; C1 = (f32x16){};                                       \
    _Pragma("unroll")                                                       \
    for (int f=0; f<4; ++f){                                                \
      const int p = f & 1, q = p ^ 1;                                       \
      const int nf = (f + 1) & 3;                                           \
      const int nt = (f == 3) ? tn_ : t_;                                   \
      bf[q] = *(const half8v*)(baseF + (size_t)nt*4096 + (size_t)nf*1024);  \
      C0 = MFMA(af[0][f], bf[p], C0);                                       \
      if (DO_EPI){                                                          \
        EPIX(P0, f*4+0, CWP, racc0); EPIX(P1, f*4+0, CWP, racc1);           \
        EPIX(P0, f*4+1, CWP, racc0); EPIX(P1, f*4+1, CWP, racc1);           \
      }                                                                     \
      C1 = MFMA(af[1][f], bf[p], C1);                                       \
      if (DO_EPI){                                                          \
        EPIX(P0, f*4+2, CWP, racc0); EPIX(P1, f*4+2, CWP, racc1);           \
        EPIX(P0, f*4+3, CWP, racc0); EPIX(P1, f*4+3, CWP, racc1);           \
      }                                                                     \
    }                                                                       \
  } while(0)

  // prologue tile (even slot), no EPI
  TILE(t0, t0+1, aE0, aE1, aO0, aO1, cwE, cwO, 0);
  int ti = 1;
  #pragma unroll 1
  for (; ti + 1 < ntl; ti += 2){
    const int To = t0 + ti, Te = t0 + ti + 1;
    const int TnO = Te;                         // next after odd tile
    const int TnE = (ti + 2 < ntl) ? Te + 1 : t0;  // wrap: prefetch unused
    TILE(To, TnO, aO0, aO1, aE0, aE1, cwO, cwE, 1);
    TILE(Te, TnE, aE0, aE1, aO0, aO1, cwE, cwO, 1);
  }
  if (ti < ntl){
    // ntl even: one final odd tile, then flush both
    TILE(t0+ti, t0, aO0, aO1, aE0, aE1, cwO, cwE, 1);
    #pragma unroll
    for (int r=0;r<16;++r){ EPIX(aO0, r, cwO, racc0); EPIX(aO1, r, cwO, racc1); }
  } else {
    // ntl odd: flush the last even tile
    #pragma unroll
    for (int r=0;r<16;++r){ EPIX(aE0, r, cwE, racc0); EPIX(aE1, r, cwE, racc1); }
  }
  #undef TILE
  #undef EPIX

  // ---- reduce over 32 col-lanes, fold 2^xn, one atomic per row ----
  #pragma unroll
  for (int rf=0; rf<2; rf++){
    #pragma unroll
    for (int r=0;r<16;r++){
      float v = rf ? racc1[r] : racc0[r];
      v += __shfl_xor(v, 1);
      v += __shfl_xor(v, 2);
      v += __shfl_xor(v, 4);
      v += __shfl_xor(v, 8);
      v += __shfl_xor(v, 16);
      const int rit = (r&3) + 8*(r>>2) + 4*h;
      const float xnv = __shfl(xn[rf], rit);
      if (cl == 0)
        atomicAdd(&out[rows0 + rf*32 + rit], v * __builtin_amdgcn_exp2f(xnv));
    }
  }
}

extern "C" void kernel_launch(void* const* d_in, const int* in_sizes, int n_in,
                              void* d_out, int out_size, void* d_ws, size_t ws_size,
                              hipStream_t stream) {
  const float* X = (const float*)d_in[0];   // [B,64]
  const float* C = (const float*)d_in[1];   // [G,64]
  const float* W = (const float*)d_in[2];   // [G]
  float* out = (float*)d_out;               // [B]
  const int B = in_sizes[0] / 64;
  const int G = in_sizes[2];

  _Float16* Cf = (_Float16*)d_ws;                // 1 MB, fragment-ordered
  float2* cw = (float2*)(Cf + (size_t)G*64);     // 64 KB

  hipMemsetAsync(out, 0, (size_t)B*sizeof(float), stream);
  convert_C<<<(G*4)/256, 256, 0, stream>>>(C, W, Cf, cw, G);
  rbf_mfma<<<(B/256)*GP, 256, 0, stream>>>(X, Cf, cw, out);
}